// Round 10
// baseline (125.979 us; speedup 1.0000x reference)
//
#include <hip/hip_runtime.h>
#include <hip/hip_bf16.h>

#define NSEQ 256
#define DIM 64
#define NB 128
#define NPAIR 384
#define FINF 1e8f
#define LOG2E 1.4426950408889634f
#define LN2 0.6931471805599453f

using f32x4 = __attribute__((ext_vector_type(4))) float;
using s16x8 = __attribute__((ext_vector_type(8))) short;

__device__ __forceinline__ unsigned short bf16u(float f) {
    __hip_bfloat16 h = __float2bfloat16(f);
    return __builtin_bit_cast(unsigned short, h);
}
__device__ __forceinline__ short bf16s(float f) {
    __hip_bfloat16 h = __float2bfloat16(f);
    return __builtin_bit_cast(short, h);
}
__device__ __forceinline__ float min3f(float a, float b, float c) {
    float d; asm("v_min3_f32 %0, %1, %2, %3" : "=v"(d) : "v"(a), "v"(b), "v"(c));
    return d;
}
__device__ __forceinline__ float max3f(float a, float b, float c) {
    float d; asm("v_max3_f32 %0, %1, %2, %3" : "=v"(d) : "v"(a), "v"(b), "v"(c));
    return d;
}

// ---------------------------------------------------------------------------
// Kernel 1: D[p][i][j] = |a_i - b_j|^2, stored DIAGONAL-MAJOR:
//   S[p][(i+j) & 255][i]. 2 blocks per pair (768 blocks, 128 rows each).
// (unchanged from round 9 — verified passing)
// ---------------------------------------------------------------------------
__global__ __launch_bounds__(256, 3)
void dist_kernel(const float* __restrict__ X, const float* __restrict__ Y,
                 unsigned short* __restrict__ S) {
    __shared__ __align__(16) short b_lds[NSEQ * DIM];   // 32 KB; reused as sbuf
    __shared__ __align__(16) short a_lds[128 * DIM];    // 16 KB (this half's A)
    __shared__ float a2[128];
    __shared__ float b2[NSEQ];
    unsigned short* sbuf = reinterpret_cast<unsigned short*>(b_lds);

    const int bid = blockIdx.x;
    const int p = bid >> 1;       // pair 0..383
    const int h = bid & 1;        // row-half 0..1
    const int b = p & (NB - 1);
    const int g = p >> 7;         // 0: (x,y)  1: (x,x)  2: (y,y)
    const float* Arow = (g == 2 ? Y : X) + (size_t)b * NSEQ * DIM
                        + (size_t)h * 128 * DIM;
    const float* Brow = (g == 1 ? X : Y) + (size_t)b * NSEQ * DIM;

    const int t = threadIdx.x;
    {
        const float4* bv = reinterpret_cast<const float4*>(Brow) + t * (DIM / 4);
        float sb = 0.f;
#pragma unroll
        for (int q = 0; q < 8; ++q) {
            float4 b0 = bv[2 * q], b1 = bv[2 * q + 1];
            sb += b0.x * b0.x + b0.y * b0.y + b0.z * b0.z + b0.w * b0.w
                + b1.x * b1.x + b1.y * b1.y + b1.z * b1.z + b1.w * b1.w;
            s16x8 pb = { bf16s(b0.x), bf16s(b0.y), bf16s(b0.z), bf16s(b0.w),
                         bf16s(b1.x), bf16s(b1.y), bf16s(b1.z), bf16s(b1.w) };
            *reinterpret_cast<s16x8*>(&b_lds[t * DIM + ((q ^ (t & 7)) << 3)]) = pb;
        }
        b2[t] = sb;
    }
    if (t < 128) {
        const float4* av = reinterpret_cast<const float4*>(Arow) + t * (DIM / 4);
        float sa = 0.f;
#pragma unroll
        for (int q = 0; q < 8; ++q) {
            float4 a0 = av[2 * q], a1 = av[2 * q + 1];
            sa += a0.x * a0.x + a0.y * a0.y + a0.z * a0.z + a0.w * a0.w
                + a1.x * a1.x + a1.y * a1.y + a1.z * a1.z + a1.w * a1.w;
            s16x8 pa = { bf16s(a0.x), bf16s(a0.y), bf16s(a0.z), bf16s(a0.w),
                         bf16s(a1.x), bf16s(a1.y), bf16s(a1.z), bf16s(a1.w) };
            *reinterpret_cast<s16x8*>(&a_lds[t * DIM + ((q ^ (t & 7)) << 3)]) = pa;
        }
        a2[t] = sa;
    }
    __syncthreads();

    const int wave = t >> 6;
    const int lane = t & 63;
    const int lrow = lane & 15;
    const int lk   = lane >> 4;

    s16x8 bfr[4][2];
    float bn[4];
#pragma unroll
    for (int ct = 0; ct < 4; ++ct) {
        const int c = 64 * wave + ct * 16 + lrow;
#pragma unroll
        for (int kk = 0; kk < 2; ++kk) {
            const int kb = kk * 4 + lk;
            bfr[ct][kk] = *reinterpret_cast<const s16x8*>(
                &b_lds[c * DIM + ((kb ^ (c & 7)) << 3)]);
        }
        bn[ct] = b2[c];
    }
    __syncthreads();  // all waves done with b_lds; it becomes sbuf now

    const size_t pbase = (size_t)p * (NSEQ * NSEQ);
#pragma unroll 1
    for (int sloc = 0; sloc < 2; ++sloc) {
        const int rl0 = sloc * 64;
        const int r0  = h * 128 + rl0;
        s16x8 afr[4][2];
#pragma unroll
        for (int rt = 0; rt < 4; ++rt) {
            const int rl = rl0 + rt * 16 + lrow;
#pragma unroll
            for (int kk = 0; kk < 2; ++kk) {
                const int kb = kk * 4 + lk;
                afr[rt][kk] = *reinterpret_cast<const s16x8*>(
                    &a_lds[rl * DIM + ((kb ^ (rl & 7)) << 3)]);
            }
        }
#pragma unroll
        for (int ct = 0; ct < 4; ++ct) {
            const int c = 64 * wave + ct * 16 + lrow;
#pragma unroll
            for (int rt = 0; rt < 4; ++rt) {
                f32x4 acc = {0.f, 0.f, 0.f, 0.f};
                acc = __builtin_amdgcn_mfma_f32_16x16x32_bf16(afr[rt][0], bfr[ct][0], acc, 0, 0, 0);
                acc = __builtin_amdgcn_mfma_f32_16x16x32_bf16(afr[rt][1], bfr[ct][1], acc, 0, 0, 0);
#pragma unroll
                for (int jv = 0; jv < 4; ++jv) {
                    const int rloc = rt * 16 + lk * 4 + jv;
                    const float dist = a2[rl0 + rloc] + bn[ct] - 2.f * acc[jv];
                    sbuf[rloc * NSEQ + (c ^ (((rloc >> 2) & 3) << 4))] = bf16u(dist);
                }
            }
        }
        __syncthreads();
        const int sl = lane >> 4;
        const int q  = lane & 15;
#pragma unroll
        for (int gg = 0; gg < 16; ++gg) {
            const int s = 64 * wave + gg * 4 + sl;
            const int il0 = 4 * q;
            const int swz = ((q & 3) << 4);
            const int j0 = (s - (r0 + il0 + 0)) & 255;
            const int j1 = (s - (r0 + il0 + 1)) & 255;
            const int j2 = (s - (r0 + il0 + 2)) & 255;
            const int j3 = (s - (r0 + il0 + 3)) & 255;
            unsigned int e0 = sbuf[(il0 + 0) * NSEQ + (j0 ^ swz)];
            unsigned int e1 = sbuf[(il0 + 1) * NSEQ + (j1 ^ swz)];
            unsigned int e2 = sbuf[(il0 + 2) * NSEQ + (j2 ^ swz)];
            unsigned int e3 = sbuf[(il0 + 3) * NSEQ + (j3 ^ swz)];
            uint2 w;
            w.x = e0 | (e1 << 16);
            w.y = e2 | (e3 << 16);
            *reinterpret_cast<uint2*>(&S[pbase + (size_t)s * NSEQ + r0 + 4 * q]) = w;
        }
        __syncthreads();
    }
}

// ---------------------------------------------------------------------------
// Kernel 2: soft-DTW DP, ROW-BAND scan. 4 bands x 64 rows; lane L owns row
// 64b+L; step t computes column j = t-L (320 steps/band incl. 1 pad).
// Cell math identical to round 6/9 (verified absmax 0.0). D staged per
// 8-step chunk with ONE global_load_lds(16B) (band's 128B slice of 8 S-rows),
// double-buffered into regs via asm ds_read_u16. Band-boundary row passed
// through a ping-pong 256-float LDS buffer (lane63 writes, lane0 reads).
// ---------------------------------------------------------------------------
#define DSRU16(dst, base, offstr) \
    asm volatile("ds_read_u16 %0, %1 offset:" offstr : "=v"(dst) : "v"(base))
#define RDD8(dsr, base) \
    DSRU16(dsr[0], base, "0");   DSRU16(dsr[1], base, "128"); \
    DSRU16(dsr[2], base, "256"); DSRU16(dsr[3], base, "384"); \
    DSRU16(dsr[4], base, "512"); DSRU16(dsr[5], base, "640"); \
    DSRU16(dsr[6], base, "768"); DSRU16(dsr[7], base, "896")
#define DSRB128(dst, base, offstr) \
    asm volatile("ds_read_b128 %0, %1 offset:" offstr : "=v"(dst) : "v"(base))
#define LGKM0() do { \
    asm volatile("s_waitcnt lgkmcnt(0)" ::: "memory"); \
    __builtin_amdgcn_sched_barrier(0); } while (0)

__global__ __launch_bounds__(64, 1)
void dtw_kernel(const unsigned short* __restrict__ S, float* __restrict__ rout) {
    __shared__ __align__(16) unsigned short sd[4 * 512];  // 4 slots x 1 KB
    __shared__ __align__(16) float bndbuf[2][256];        // ping-pong boundary
    const int p = blockIdx.x;
    const int L = threadIdx.x;
    const unsigned short* Sp = S + (size_t)p * (NSEQ * NSEQ);
    const bool lz = (L == 0);
    const int lrow = L >> 3, lcol = L & 7;

    // band 0's upper boundary: R[-1][j] = INF
    bndbuf[0][L] = FINF; bndbuf[0][L + 64] = FINF;
    bndbuf[0][L + 128] = FINF; bndbuf[0][L + 192] = FINF;

    // stage chunk (band, cc): 8 S-rows (64*band+8cc ..)&255, 128B band-slice
    auto stage = [&](int band, int cc) {
        const int row = (64 * band + 8 * cc + lrow) & 255;
        const int slice = band & 3;  // band 4 wraps to valid, never-consumed data
        const char* src = (const char*)Sp + row * 512 + slice * 128 + lcol * 16;
        __builtin_amdgcn_global_load_lds(
            (const __attribute__((address_space(1))) void*)src,
            (__attribute__((address_space(3))) void*)&sd[(cc & 3) * 512],
            16, 0, 0);  // dest = uniform base + lane*16 (linear)
    };

    const unsigned sdbyte = (unsigned)(uintptr_t)
        (__attribute__((address_space(3))) unsigned short*)&sd[0];
    const unsigned bndbyte = (unsigned)(uintptr_t)
        (__attribute__((address_space(3))) float*)&bndbuf[0][0];

    const int finf_bits = __builtin_bit_cast(int, FINF);
    float s1, s2, rp, carry;

    // one cell: R'[i][j] = D*log2e + softmin2(a,b,c); returns new value
    auto stepfn = [&](unsigned du, float bt, float btm1) -> float {
        const float dv = __builtin_bit_cast(float, du << 16);
        const float bb = lz ? bt : s1;     // R'[i-1][j]
        const float a  = lz ? btm1 : s2;   // R'[i-1][j-1]
        const float m   = min3f(a, bb, rp);
        const float med = __builtin_amdgcn_fmed3f(a, bb, rp);
        const float M   = max3f(a, bb, rp);
        const float e = 1.0f + __builtin_amdgcn_exp2f(m - med)
                             + __builtin_amdgcn_exp2f(m - M);
        const float sm = m - __builtin_amdgcn_logf(e);  // v_log_f32 = log2
        const float rn = __builtin_fmaf(dv, LOG2E, sm);
        s2 = s1;
        s1 = __builtin_bit_cast(float,
            __builtin_amdgcn_update_dpp(finf_bits, __builtin_bit_cast(int, rn),
                                        0x138 /*wave_shr:1*/, 0xF, 0xF, false));
        rp = rn;
        return rn;
    };

    // 8 steps of chunk (band, cc) from registers; lane63 -> boundary buffer
    auto do8 = [&](const unsigned (&dsr)[8], const f32x4 (&bw)[2],
                   int band, int cc) {
        float rb[8];
        rb[0] = stepfn(dsr[0], bw[0][0], carry);
        rb[1] = stepfn(dsr[1], bw[0][1], bw[0][0]);
        rb[2] = stepfn(dsr[2], bw[0][2], bw[0][1]);
        rb[3] = stepfn(dsr[3], bw[0][3], bw[0][2]);
        rb[4] = stepfn(dsr[4], bw[1][0], bw[0][3]);
        rb[5] = stepfn(dsr[5], bw[1][1], bw[1][0]);
        rb[6] = stepfn(dsr[6], bw[1][2], bw[1][1]);
        rb[7] = stepfn(dsr[7], bw[1][3], bw[1][2]);
        carry = bw[1][3];
        if (L == 63) {
            float* wb = &bndbuf[(band + 1) & 1][0];
            const int j0 = 8 * cc - 63;
#pragma unroll
            for (int u = 0; u < 8; ++u)
                if ((unsigned)(j0 + u) < 256u) wb[j0 + u] = rb[u];
        }
    };

    unsigned dsrA[8], dsrB[8];
    f32x4 bwA[2], bwB[2];

    auto rdchunk = [&](unsigned (&dsr)[8], f32x4 (&bw)[2], int band, int cc) {
        const unsigned dbase = sdbyte + ((cc & 3) << 10) + (L << 1);
        RDD8(dsr, dbase);
        const unsigned bbase = bndbyte + ((band & 1) << 10) + (cc << 5);
        DSRB128(bw[0], bbase, "0");
        DSRB128(bw[1], bbase, "16");
    };

    // prologue: chunks (0,0..2); chunk 0 landed after vmcnt(2)
    stage(0, 0); stage(0, 1); stage(0, 2);
    asm volatile("s_waitcnt vmcnt(2)" ::: "memory");
    rdchunk(dsrA, bwA, 0, 0);
    LGKM0();

#pragma unroll 1
    for (int band = 0; band < 4; ++band) {
        s1 = FINF; s2 = FINF; rp = FINF;
        carry = (band == 0) ? 0.f : FINF;  // R[-1][-1]=0 only at very start
#pragma unroll 1
        for (int cit = 0; cit < 20; ++cit) {
            const int cc = 2 * cit;
            // ---- consume chunk cc (A); prefetch cc+1 regs (B)
            { int sb = band, sc = cc + 3;
              if (sc >= 40) { sb++; sc -= 40; }
              stage(sb, sc); }
            asm volatile("s_waitcnt vmcnt(2)" ::: "memory");
            rdchunk(dsrB, bwB, band, cc + 1);  // cc+1 <= 39
            do8(dsrA, bwA, band, cc);
            LGKM0();
            // ---- consume chunk cc+1 (B); prefetch cc+2 regs (A)
            { int sb = band, sc = cc + 4;
              if (sc >= 40) { sb++; sc -= 40; }
              stage(sb, sc); }
            asm volatile("s_waitcnt vmcnt(2)" ::: "memory");
            { int rb2 = band, rc2 = cc + 2;
              if (rc2 >= 40) { rb2++; rc2 -= 40; }
              rdchunk(dsrA, bwA, rb2, rc2); }   // crosses into next band's c0
            do8(dsrB, bwB, band, cc + 1);
            LGKM0();
        }
    }

    asm volatile("s_waitcnt vmcnt(0)" ::: "memory");  // drain dangling stages
    // R[255][255] written by band 3 (lane 63, t=318) into bndbuf[0][255]
    if (lz) rout[p] = bndbuf[0][255] * LN2;
}

// ---------------------------------------------------------------------------
// Kernel 3: loss = mean_b( r[b] - 0.5*(r[b+128] + r[b+256]) ) + 1e-5
// ---------------------------------------------------------------------------
__global__ void reduce_kernel(const float* __restrict__ rr, float* __restrict__ out) {
    const int t = threadIdx.x;  // 128 threads
    float v = rr[t] - 0.5f * (rr[t + 128] + rr[t + 256]);
#pragma unroll
    for (int o = 32; o > 0; o >>= 1) v += __shfl_down(v, o);
    __shared__ float sred[2];
    if ((t & 63) == 0) sred[t >> 6] = v;
    __syncthreads();
    if (t == 0) out[0] = (sred[0] + sred[1]) * (1.f / 128.f) + 1e-5f;
}

extern "C" void kernel_launch(void* const* d_in, const int* in_sizes, int n_in,
                              void* d_out, int out_size, void* d_ws, size_t ws_size,
                              hipStream_t stream) {
    const float* X = (const float*)d_in[0];  // outputs (128,256,64) f32
    const float* Y = (const float*)d_in[1];  // targets (128,256,64) f32
    float* out = (float*)d_out;

    const size_t dbytes = (size_t)NPAIR * NSEQ * NSEQ * sizeof(unsigned short);
    const size_t need = dbytes + (size_t)NPAIR * sizeof(float);
    if (ws_size < need) {
        hipMemsetAsync(d_out, 0x7f, sizeof(float), stream);  // sentinel
        return;
    }
    unsigned short* Sws = (unsigned short*)d_ws;
    float* rws = (float*)((char*)d_ws + dbytes);

    dist_kernel<<<2 * NPAIR, 256, 0, stream>>>(X, Y, Sws);
    dtw_kernel<<<NPAIR, 64, 0, stream>>>(Sws, rws);
    reduce_kernel<<<1, 128, 0, stream>>>(rws, out);
}

// Round 12
// 91.036 us; speedup vs baseline: 1.3838x; 1.3838x over previous
//
#include <hip/hip_runtime.h>
#include <hip/hip_bf16.h>

#define NSEQ 256
#define DIM 64
#define NB 128
#define NPAIR 384
#define FINF 1e8f
#define LOG2E 1.4426950408889634f
#define LN2 0.6931471805599453f

using f32x4 = __attribute__((ext_vector_type(4))) float;
using s16x8 = __attribute__((ext_vector_type(8))) short;

__device__ __forceinline__ unsigned short bf16u(float f) {
    __hip_bfloat16 h = __float2bfloat16(f);
    return __builtin_bit_cast(unsigned short, h);
}
__device__ __forceinline__ short bf16s(float f) {
    __hip_bfloat16 h = __float2bfloat16(f);
    return __builtin_bit_cast(short, h);
}
__device__ __forceinline__ float min3f(float a, float b, float c) {
    float d; asm("v_min3_f32 %0, %1, %2, %3" : "=v"(d) : "v"(a), "v"(b), "v"(c));
    return d;
}
__device__ __forceinline__ float max3f(float a, float b, float c) {
    float d; asm("v_max3_f32 %0, %1, %2, %3" : "=v"(d) : "v"(a), "v"(b), "v"(c));
    return d;
}

// ---------------------------------------------------------------------------
// Kernel 1: D[p][i][j] = |a_i - b_j|^2, stored DIAGONAL-MAJOR:
//   S[p][(i+j) & 255][i]. 2 blocks per pair. (unchanged — verified passing)
// ---------------------------------------------------------------------------
__global__ __launch_bounds__(256, 3)
void dist_kernel(const float* __restrict__ X, const float* __restrict__ Y,
                 unsigned short* __restrict__ S) {
    __shared__ __align__(16) short b_lds[NSEQ * DIM];   // 32 KB; reused as sbuf
    __shared__ __align__(16) short a_lds[128 * DIM];    // 16 KB (this half's A)
    __shared__ float a2[128];
    __shared__ float b2[NSEQ];
    unsigned short* sbuf = reinterpret_cast<unsigned short*>(b_lds);

    const int bid = blockIdx.x;
    const int p = bid >> 1;       // pair 0..383
    const int h = bid & 1;        // row-half 0..1
    const int b = p & (NB - 1);
    const int g = p >> 7;         // 0: (x,y)  1: (x,x)  2: (y,y)
    const float* Arow = (g == 2 ? Y : X) + (size_t)b * NSEQ * DIM
                        + (size_t)h * 128 * DIM;
    const float* Brow = (g == 1 ? X : Y) + (size_t)b * NSEQ * DIM;

    const int t = threadIdx.x;
    {
        const float4* bv = reinterpret_cast<const float4*>(Brow) + t * (DIM / 4);
        float sb = 0.f;
#pragma unroll
        for (int q = 0; q < 8; ++q) {
            float4 b0 = bv[2 * q], b1 = bv[2 * q + 1];
            sb += b0.x * b0.x + b0.y * b0.y + b0.z * b0.z + b0.w * b0.w
                + b1.x * b1.x + b1.y * b1.y + b1.z * b1.z + b1.w * b1.w;
            s16x8 pb = { bf16s(b0.x), bf16s(b0.y), bf16s(b0.z), bf16s(b0.w),
                         bf16s(b1.x), bf16s(b1.y), bf16s(b1.z), bf16s(b1.w) };
            *reinterpret_cast<s16x8*>(&b_lds[t * DIM + ((q ^ (t & 7)) << 3)]) = pb;
        }
        b2[t] = sb;
    }
    if (t < 128) {
        const float4* av = reinterpret_cast<const float4*>(Arow) + t * (DIM / 4);
        float sa = 0.f;
#pragma unroll
        for (int q = 0; q < 8; ++q) {
            float4 a0 = av[2 * q], a1 = av[2 * q + 1];
            sa += a0.x * a0.x + a0.y * a0.y + a0.z * a0.z + a0.w * a0.w
                + a1.x * a1.x + a1.y * a1.y + a1.z * a1.z + a1.w * a1.w;
            s16x8 pa = { bf16s(a0.x), bf16s(a0.y), bf16s(a0.z), bf16s(a0.w),
                         bf16s(a1.x), bf16s(a1.y), bf16s(a1.z), bf16s(a1.w) };
            *reinterpret_cast<s16x8*>(&a_lds[t * DIM + ((q ^ (t & 7)) << 3)]) = pa;
        }
        a2[t] = sa;
    }
    __syncthreads();

    const int wave = t >> 6;
    const int lane = t & 63;
    const int lrow = lane & 15;
    const int lk   = lane >> 4;

    s16x8 bfr[4][2];
    float bn[4];
#pragma unroll
    for (int ct = 0; ct < 4; ++ct) {
        const int c = 64 * wave + ct * 16 + lrow;
#pragma unroll
        for (int kk = 0; kk < 2; ++kk) {
            const int kb = kk * 4 + lk;
            bfr[ct][kk] = *reinterpret_cast<const s16x8*>(
                &b_lds[c * DIM + ((kb ^ (c & 7)) << 3)]);
        }
        bn[ct] = b2[c];
    }
    __syncthreads();  // all waves done with b_lds; it becomes sbuf now

    const size_t pbase = (size_t)p * (NSEQ * NSEQ);
#pragma unroll 1
    for (int sloc = 0; sloc < 2; ++sloc) {
        const int rl0 = sloc * 64;
        const int r0  = h * 128 + rl0;
        s16x8 afr[4][2];
#pragma unroll
        for (int rt = 0; rt < 4; ++rt) {
            const int rl = rl0 + rt * 16 + lrow;
#pragma unroll
            for (int kk = 0; kk < 2; ++kk) {
                const int kb = kk * 4 + lk;
                afr[rt][kk] = *reinterpret_cast<const s16x8*>(
                    &a_lds[rl * DIM + ((kb ^ (rl & 7)) << 3)]);
            }
        }
#pragma unroll
        for (int ct = 0; ct < 4; ++ct) {
            const int c = 64 * wave + ct * 16 + lrow;
#pragma unroll
            for (int rt = 0; rt < 4; ++rt) {
                f32x4 acc = {0.f, 0.f, 0.f, 0.f};
                acc = __builtin_amdgcn_mfma_f32_16x16x32_bf16(afr[rt][0], bfr[ct][0], acc, 0, 0, 0);
                acc = __builtin_amdgcn_mfma_f32_16x16x32_bf16(afr[rt][1], bfr[ct][1], acc, 0, 0, 0);
#pragma unroll
                for (int jv = 0; jv < 4; ++jv) {
                    const int rloc = rt * 16 + lk * 4 + jv;
                    const float dist = a2[rl0 + rloc] + bn[ct] - 2.f * acc[jv];
                    sbuf[rloc * NSEQ + (c ^ (((rloc >> 2) & 3) << 4))] = bf16u(dist);
                }
            }
        }
        __syncthreads();
        const int sl = lane >> 4;
        const int q  = lane & 15;
#pragma unroll
        for (int gg = 0; gg < 16; ++gg) {
            const int s = 64 * wave + gg * 4 + sl;
            const int il0 = 4 * q;
            const int swz = ((q & 3) << 4);
            const int j0 = (s - (r0 + il0 + 0)) & 255;
            const int j1 = (s - (r0 + il0 + 1)) & 255;
            const int j2 = (s - (r0 + il0 + 2)) & 255;
            const int j3 = (s - (r0 + il0 + 3)) & 255;
            unsigned int e0 = sbuf[(il0 + 0) * NSEQ + (j0 ^ swz)];
            unsigned int e1 = sbuf[(il0 + 1) * NSEQ + (j1 ^ swz)];
            unsigned int e2 = sbuf[(il0 + 2) * NSEQ + (j2 ^ swz)];
            unsigned int e3 = sbuf[(il0 + 3) * NSEQ + (j3 ^ swz)];
            uint2 w;
            w.x = e0 | (e1 << 16);
            w.y = e2 | (e3 << 16);
            *reinterpret_cast<uint2*>(&S[pbase + (size_t)s * NSEQ + r0 + 4 * q]) = w;
        }
        __syncthreads();
    }
}

// ---------------------------------------------------------------------------
// Kernel 2: soft-DTW DP, 4 COOPERATIVE WAVES per pair (256-thread block).
// Wave w owns rows [64w,64w+64), lane L = row 64w+L. Chunks of 16 diagonals;
// wave w runs chunk c at round r = c+w (chunks [4w, 4w+19]); 35 rounds with
// one __syncthreads() per round (full vmcnt+lgkm drain -> no visibility or
// counting subtleties; staging issued at round end lands by next round's
// drain, hidden under ~1200cy of steps). Boundary row (lane63 -> next wave's
// lane0) via plain-C LDS slots of 18 floats: [0]=carB (prev-chunk entry 14),
// [1]=carA (entry 15), [2..17]=this chunk's 16 row-values. Writer posts its
// rb[14],rb[15] into the NEXT slot's carry fields. Rail cells (~1e8) self-
// sustain; staleness past writer's last chunk confined to j>=256 cells.
// Cell math verbatim from verified rounds 6/9/10 (absmax 0.0).
// ---------------------------------------------------------------------------
__global__ __launch_bounds__(256, 1)
void dtw_kernel(const unsigned short* __restrict__ S, float* __restrict__ rout) {
    __shared__ __align__(16) unsigned short sdD[4 * 4 * 1024];  // 32 KB
    __shared__ __align__(16) float bndN[4][4][18];              // 1.1 KB
    const int p = blockIdx.x;
    const int t = threadIdx.x;
    const int w = t >> 6;     // wave 0..3
    const int L = t & 63;
    const unsigned short* Sp = S + (size_t)p * (NSEQ * NSEQ);
    const int cfirst = 4 * w, clast = 4 * w + 19;
    const int lrow = L >> 3, lcol = L & 7;
    const bool lz = (L == 0);

    auto stageck = [&](int cc) {  // 16 rows x 128B slice -> slot cc&3 (2 loads)
        const int slot = cc & 3;
#pragma unroll
        for (int k = 0; k < 2; ++k) {
            const int row = (16 * cc + 8 * k + lrow) & 255;
            const char* src = (const char*)Sp + row * 512 + w * 128 + lcol * 16;
            __builtin_amdgcn_global_load_lds(
                (const __attribute__((address_space(1))) void*)src,
                (__attribute__((address_space(3))) void*)
                    &sdD[w * 4096 + slot * 1024 + k * 512],
                16, 0, 0);
        }
    };

    stageck(cfirst); stageck(cfirst + 1); stageck(cfirst + 2);

    float s1 = FINF, s2 = FINF, rp = FINF;
    const int finf_bits = __builtin_bit_cast(int, FINF);
    float out_val = 0.f;

    // verbatim verified cell: bt = R[i-1][j], btm1 = R[i-1][j-1] (lane0 only)
    auto stepfn = [&](float dv, float bt, float btm1) -> float {
        const float bb = lz ? bt : s1;
        const float a  = lz ? btm1 : s2;
        const float m   = min3f(a, bb, rp);
        const float med = __builtin_amdgcn_fmed3f(a, bb, rp);
        const float M   = max3f(a, bb, rp);
        const float e = 1.0f + __builtin_amdgcn_exp2f(m - med)
                             + __builtin_amdgcn_exp2f(m - M);
        const float sm = m - __builtin_amdgcn_logf(e);  // v_log_f32 = log2
        const float rn = __builtin_fmaf(dv, LOG2E, sm);
        s2 = s1;
        s1 = __builtin_bit_cast(float,
            __builtin_amdgcn_update_dpp(finf_bits, __builtin_bit_cast(int, rn),
                                        0x138 /*wave_shr:1*/, 0xF, 0xF, false));
        rp = rn;
        return rn;
    };

#pragma unroll 1
    for (int r = 0; r < 35; ++r) {
        __syncthreads();  // full drain + barrier: staging landed, bnd visible
        const int c = r - w;
        if (c >= cfirst && c <= clast) {
            // --- D values for this chunk: row u at short-offset u*64, lane L
            float dvv[16];
            {
                const unsigned short* db = &sdD[w * 4096 + (c & 3) * 1024 + L];
#pragma unroll
                for (int u = 0; u < 16; ++u)
                    dvv[u] = __builtin_bit_cast(float, (unsigned)db[u * 64] << 16);
            }
            // --- boundary from wave w-1 ---
            float bwf[16], carA, carB;
            if (w == 0) {
#pragma unroll
                for (int u = 0; u < 16; ++u) bwf[u] = FINF;
                carA = FINF;
                carB = (c == 0) ? 0.f : FINF;  // R[-1][-1] = 0 at very start
            } else {
                const float* bs = &bndN[w][c & 3][0];
                carB = bs[0];
                carA = bs[1];
#pragma unroll
                for (int u = 0; u < 16; ++u) bwf[u] = bs[2 + u];
            }
            // --- 16 steps ---
            float rb[16];
            rb[0] = stepfn(dvv[0], carA, carB);
            rb[1] = stepfn(dvv[1], bwf[0], carA);
#pragma unroll
            for (int u = 2; u < 16; ++u)
                rb[u] = stepfn(dvv[u], bwf[u - 1], bwf[u - 2]);

            // --- publish boundary for wave w+1 ---
            if (w < 3) {
                if (L == 63) {
                    float* bd = &bndN[w + 1][c & 3][0];
#pragma unroll
                    for (int u = 0; u < 16; ++u) bd[2 + u] = rb[u];
                    float* bd2 = &bndN[w + 1][(c + 1) & 3][0];
                    bd2[0] = rb[14];  // carB for reader chunk c+1
                    bd2[1] = rb[15];  // carA for reader chunk c+1
                }
            } else if (c == 31 && L == 63) {
                out_val = rb[14];  // step 510 = R[255][255]
            }
            if (c + 3 <= clast) stageck(c + 3);
        }
    }

    if (w == 3 && L == 63) rout[p] = out_val * LN2;  // base-2 -> nats
}

// ---------------------------------------------------------------------------
// Kernel 3: loss = mean_b( r[b] - 0.5*(r[b+128] + r[b+256]) ) + 1e-5
// ---------------------------------------------------------------------------
__global__ void reduce_kernel(const float* __restrict__ rr, float* __restrict__ out) {
    const int t = threadIdx.x;  // 128 threads
    float v = rr[t] - 0.5f * (rr[t + 128] + rr[t + 256]);
#pragma unroll
    for (int o = 32; o > 0; o >>= 1) v += __shfl_down(v, o);
    __shared__ float sred[2];
    if ((t & 63) == 0) sred[t >> 6] = v;
    __syncthreads();
    if (t == 0) out[0] = (sred[0] + sred[1]) * (1.f / 128.f) + 1e-5f;
}

extern "C" void kernel_launch(void* const* d_in, const int* in_sizes, int n_in,
                              void* d_out, int out_size, void* d_ws, size_t ws_size,
                              hipStream_t stream) {
    const float* X = (const float*)d_in[0];  // outputs (128,256,64) f32
    const float* Y = (const float*)d_in[1];  // targets (128,256,64) f32
    float* out = (float*)d_out;

    const size_t dbytes = (size_t)NPAIR * NSEQ * NSEQ * sizeof(unsigned short);
    const size_t need = dbytes + (size_t)NPAIR * sizeof(float);
    if (ws_size < need) {
        hipMemsetAsync(d_out, 0x7f, sizeof(float), stream);  // sentinel
        return;
    }
    unsigned short* Sws = (unsigned short*)d_ws;
    float* rws = (float*)((char*)d_ws + dbytes);

    dist_kernel<<<2 * NPAIR, 256, 0, stream>>>(X, Y, Sws);
    dtw_kernel<<<NPAIR, 256, 0, stream>>>(Sws, rws);
    reduce_kernel<<<1, 128, 0, stream>>>(rws, out);
}